// Round 3
// baseline (1472.705 us; speedup 1.0000x reference)
//
#include <hip/hip_runtime.h>

typedef _Float16 f16;
typedef _Float16 f16x4 __attribute__((ext_vector_type(4)));
typedef _Float16 f16x8 __attribute__((ext_vector_type(8)));
typedef float f32x4 __attribute__((ext_vector_type(4)));

#define NBATCH 4096
#define RMAX 200   // max segment rows held in LDS; mean=122, sd~11, max over 4096 ~ 170

__device__ __forceinline__ f32x4 mfma16(f16x8 a, f16x8 b, f32x4 c) {
  return __builtin_amdgcn_mfma_f32_16x16x32_f16(a, b, c, 0, 0, 0);
}

// XOR swizzle: keeps 8-f16 chunks contiguous+16B-aligned, spreads row stride across banks
__device__ __forceinline__ int swz(int r, int c) { return r * 128 + (c ^ ((r & 7) << 3)); }

// ---------------- segment bounds: seg[s] = first i with batch[i] >= s ----------------
__global__ void seg_bounds(const int* __restrict__ batch, int N, int NB, int* __restrict__ seg) {
  int s = blockIdx.x * blockDim.x + threadIdx.x;
  if (s > NB) return;
  int lo = 0, hi = N;
  while (lo < hi) { int mid = (lo + hi) >> 1; if (batch[mid] < s) lo = mid + 1; else hi = mid; }
  seg[s] = lo;
}

// ---------------- pack 10 fp32 128x128 weights into MFMA B-frag order, fp16 ----------------
__global__ void pack_weights(const float* w0, const float* w1, const float* w2, const float* w3,
                             const float* w4, const float* w5, const float* w6, const float* w7,
                             const float* w8, const float* w9, f16* __restrict__ Wp) {
  int idx = blockIdx.x * blockDim.x + threadIdx.x;
  if (idx >= 10 * 16384) return;
  int w = idx >> 14, p = idx & 16383;
  int j = p & 7, lane = (p >> 3) & 63, nt = (p >> 9) & 7, kk = p >> 12;
  int k = kk * 32 + (lane >> 4) * 8 + j;
  int n = nt * 16 + (lane & 15);
  const float* W;
  switch (w) {
    case 0: W = w0; break; case 1: W = w1; break; case 2: W = w2; break;
    case 3: W = w3; break; case 4: W = w4; break; case 5: W = w5; break;
    case 6: W = w6; break; case 7: W = w7; break; case 8: W = w8; break;
    default: W = w9; break;
  }
  Wp[idx] = (f16)W[k * 128 + n];
}

// ---------------- in-LDS GEMM + bias: D[rows,128] = S[rows,128] @ W + b (fp16) ----------------
// 16 waves: mq = wave&3 owns m-tiles t ≡ mq (mod 4); nq = wave>>2 owns 32 cols (2 n-tiles).
__device__ __forceinline__ void gemm_bias_phase(const f16* S, f16* D, const f16* __restrict__ Wg,
    const float* __restrict__ bias, int rows, int mq, int nq, int lane, int quad, int li) {
  int ntl = (rows + 15) >> 4;
  f16x8 bF[4][2];
#pragma unroll
  for (int kk = 0; kk < 4; ++kk)
#pragma unroll
    for (int j = 0; j < 2; ++j)
      bF[kk][j] = *(const f16x8*)(Wg + (size_t)(((kk * 8 + nq * 2 + j) * 64 + lane) * 8));
  float bc[2];
#pragma unroll
  for (int j = 0; j < 2; ++j) bc[j] = bias[(nq * 2 + j) * 16 + li];
  for (int t = mq; t < ntl; t += 4) {
    int m0 = t * 16;
    f32x4 acc0 = {0.f, 0.f, 0.f, 0.f}, acc1 = {0.f, 0.f, 0.f, 0.f};
    int rl = m0 + li;
    bool ok = rl < rows;
#pragma unroll
    for (int kk = 0; kk < 4; ++kk) {
      f16x8 aF = {};
      if (ok) aF = *(const f16x8*)(S + swz(rl, kk * 32 + quad * 8));
      acc0 = mfma16(aF, bF[kk][0], acc0);
      acc1 = mfma16(aF, bF[kk][1], acc1);
    }
#pragma unroll
    for (int r = 0; r < 4; ++r) {
      int row = m0 + quad * 4 + r;
      if (row < rows) {
        D[swz(row, (nq * 2) * 16 + li)] = (f16)(acc0[r] + bc[0]);
        D[swz(row, (nq * 2 + 1) * 16 + li)] = (f16)(acc1[r] + bc[1]);
      }
    }
  }
}

// ---------------- in-LDS LayerNorm + Mish, in place; 4 threads/row, single shot ----------------
__device__ __forceinline__ void ln_mish_pass(f16* D, const float* __restrict__ g,
                                             const float* __restrict__ bn, int rows, int tid) {
  int part = tid & 3;
  int r = tid >> 2;               // 0..255 covers all rows (<= RMAX)
  if (r < rows) {
    float gv[32], bv[32];
#pragma unroll
    for (int j = 0; j < 8; ++j) {
      float4 gg = *(const float4*)(g + part * 32 + j * 4);
      float4 bb = *(const float4*)(bn + part * 32 + j * 4);
      gv[j * 4 + 0] = gg.x; gv[j * 4 + 1] = gg.y; gv[j * 4 + 2] = gg.z; gv[j * 4 + 3] = gg.w;
      bv[j * 4 + 0] = bb.x; bv[j * 4 + 1] = bb.y; bv[j * 4 + 2] = bb.z; bv[j * 4 + 3] = bb.w;
    }
    f16x8 v[4];
    float s1 = 0.f, s2 = 0.f;
#pragma unroll
    for (int j = 0; j < 4; ++j) {
      v[j] = *(const f16x8*)(D + swz(r, part * 32 + j * 8));
#pragma unroll
      for (int e = 0; e < 8; ++e) { float f = (float)v[j][e]; s1 += f; s2 += f * f; }
    }
    s1 += __shfl_xor(s1, 1, 64); s2 += __shfl_xor(s2, 1, 64);
    s1 += __shfl_xor(s1, 2, 64); s2 += __shfl_xor(s2, 2, 64);
    float mean = s1 * (1.f / 128.f);
    float var = s2 * (1.f / 128.f) - mean * mean;
    float rstd = rsqrtf(var + 1e-5f);
#pragma unroll
    for (int j = 0; j < 4; ++j) {
      f16x8 o;
#pragma unroll
      for (int e = 0; e < 8; ++e) {
        float u = ((float)v[j][e] - mean) * rstd * gv[j * 8 + e] + bv[j * 8 + e];
        float t = __expf(u);
        float w = t * t + 2.f * t;
        float res = (u > 20.f) ? u : u * (w / (w + 2.f));
        o[e] = (f16)res;
      }
      *(f16x8*)(D + swz(r, part * 32 + j * 8)) = o;
    }
  }
}

// ---------------- block-local per-column softmax, register-resident values ----------------
// 1024 threads: c = tid&127, stripe st = tid>>7 (8 stripes over rows).
__device__ __forceinline__ void softmax_phase(f16* P, int rows, int tid, float* scr) {
  int c = tid & 127, st = tid >> 7;
  float v[25];
#pragma unroll
  for (int i = 0; i < 25; ++i) {
    int r = st + i * 8;
    v[i] = (r < rows) ? (float)P[swz(r, c)] : -3.4e38f;
  }
  float m = v[0];
#pragma unroll
  for (int i = 1; i < 25; ++i) m = fmaxf(m, v[i]);
  scr[st * 128 + c] = m;
  __syncthreads();
  if (tid < 128) {
    float M = scr[tid];
#pragma unroll
    for (int k = 1; k < 8; ++k) M = fmaxf(M, scr[k * 128 + tid]);
    scr[tid] = M;
  }
  __syncthreads();
  float M = scr[c];
  float d = 0.f;
#pragma unroll
  for (int i = 0; i < 25; ++i) { v[i] = __expf(v[i] - M); d += v[i]; }
  __syncthreads();  // everyone has read scr[c] before reuse
  scr[st * 128 + c] = d;
  __syncthreads();
  if (tid < 128) {
    float D = 0.f;
#pragma unroll
    for (int k = 0; k < 8; ++k) D += scr[k * 128 + tid];
    scr[tid] = (D > 0.f) ? 1.f / D : 0.f;
  }
  __syncthreads();
  float inv = scr[c];
#pragma unroll
  for (int i = 0; i < 25; ++i) {
    int r = st + i * 8;
    if (r < rows) P[swz(r, c)] = (f16)(v[i] * inv);
  }
  __syncthreads();
}

// ---------------- paired GEMMs + bias, product, block-local segment sum -> global row ----------------
__device__ __forceinline__ void pairsum_phase(const f16* S1, const f16* __restrict__ W1,
    const float* __restrict__ b1, const f16* S2, const f16* __restrict__ W2,
    const float* __restrict__ b2, float* __restrict__ outp, int s, int rows,
    int mq, int nq, int lane, int quad, int li, float* red, int tid) {
  f16x8 bF1[4][2], bF2[4][2];
#pragma unroll
  for (int kk = 0; kk < 4; ++kk)
#pragma unroll
    for (int j = 0; j < 2; ++j) {
      size_t off = (size_t)(((kk * 8 + nq * 2 + j) * 64 + lane) * 8);
      bF1[kk][j] = *(const f16x8*)(W1 + off);
      bF2[kk][j] = *(const f16x8*)(W2 + off);
    }
  float b1c[2], b2c[2];
#pragma unroll
  for (int j = 0; j < 2; ++j) {
    b1c[j] = b1[(nq * 2 + j) * 16 + li];
    b2c[j] = b2[(nq * 2 + j) * 16 + li];
  }
  float zs0 = 0.f, zs1 = 0.f;
  int ntl = (rows + 15) >> 4;
  for (int t = mq; t < ntl; t += 4) {
    int m0 = t * 16;
    f32x4 a10 = {0.f,0.f,0.f,0.f}, a11 = {0.f,0.f,0.f,0.f};
    f32x4 a20 = {0.f,0.f,0.f,0.f}, a21 = {0.f,0.f,0.f,0.f};
    int rl = m0 + li;
    bool ok = rl < rows;
#pragma unroll
    for (int kk = 0; kk < 4; ++kk) {
      f16x8 aF1 = {}, aF2 = {};
      if (ok) {
        aF1 = *(const f16x8*)(S1 + swz(rl, kk * 32 + quad * 8));
        aF2 = *(const f16x8*)(S2 + swz(rl, kk * 32 + quad * 8));
      }
      a10 = mfma16(aF1, bF1[kk][0], a10);
      a11 = mfma16(aF1, bF1[kk][1], a11);
      a20 = mfma16(aF2, bF2[kk][0], a20);
      a21 = mfma16(aF2, bF2[kk][1], a21);
    }
    float cs0 = 0.f, cs1 = 0.f;
#pragma unroll
    for (int r = 0; r < 4; ++r) {
      int row = m0 + quad * 4 + r;
      if (row < rows) {
        cs0 += (a10[r] + b1c[0]) * (a20[r] + b2c[0]);
        cs1 += (a11[r] + b1c[1]) * (a21[r] + b2c[1]);
      }
    }
    cs0 += __shfl_xor(cs0, 16, 64); cs0 += __shfl_xor(cs0, 32, 64);
    cs1 += __shfl_xor(cs1, 16, 64); cs1 += __shfl_xor(cs1, 32, 64);
    zs0 += cs0; zs1 += cs1;
  }
  int wave = tid >> 6;
  red[tid] = 0.f; red[tid + 1024] = 0.f;
  __syncthreads();
  if (quad == 0) {
    red[wave * 128 + (nq * 2) * 16 + li] = zs0;
    red[wave * 128 + (nq * 2 + 1) * 16 + li] = zs1;
  }
  __syncthreads();
  if (tid < 128) {
    float ssum = 0.f;
#pragma unroll
    for (int w = 0; w < 16; ++w) ssum += red[w * 128 + tid];
    outp[(size_t)s * 128 + tid] = ssum;
  }
  __syncthreads();
}

// ---------------- the fused per-segment encoder ----------------
__global__ __launch_bounds__(1024) void encoder_mega(
    const float* __restrict__ x, const int* __restrict__ seg, const f16* __restrict__ Wp,
    const float* b_map, const float* kb1, const float* kg, const float* kbn, const float* kb2,
    const float* vb1, const float* vg, const float* vbn, const float* vb2,
    const float* ib_map, const float* ikb1, const float* ikg, const float* ikbn,
    const float* ikb2, const float* ivb1, const float* ivg, const float* ivbn,
    const float* ivb2, float* __restrict__ Z, float* __restrict__ KE) {
  __shared__ f16 L0[RMAX * 128];
  __shared__ f16 L1[RMAX * 128];
  __shared__ f16 L2[RMAX * 128];
  __shared__ float scr[2048];   // softmax stripes (1024) / pairsum red (2048)
  int s = blockIdx.x;
  int a = seg[s], e = seg[s + 1];
  int rows = e - a;
  int tid = threadIdx.x;
  if (rows <= 0) {
    if (tid < 128) {
      Z[(size_t)s * 128 + tid] = 0.f;
      KE[(size_t)s * 128 + tid] = 0.f;
    }
    return;
  }
  if (rows > RMAX) rows = RMAX;  // statistically unreachable; prevents LDS corruption
  int lane = tid & 63, wave = tid >> 6, quad = lane >> 4, li = lane & 15;
  int mq = wave & 3, nq = wave >> 2;

  // P0: x -> L0 (fp16, swizzled)
  const float* xa = x + (size_t)a * 128;
  for (int i = tid * 4; i < rows * 128; i += 4096) {
    float4 v = *(const float4*)(xa + i);
    f16x4 h;
    h[0] = (f16)v.x; h[1] = (f16)v.y; h[2] = (f16)v.z; h[3] = (f16)v.w;
    *(f16x4*)(L0 + swz(i >> 7, i & 127)) = h;
  }
  __syncthreads();
  // P1: key0 = x @ W_map + b_map -> L1
  gemm_bias_phase(L0, L1, Wp + 0 * 16384, b_map, rows, mq, nq, lane, quad, li);
  __syncthreads();
  // P2: keys = softmax(key0)  (in place, L1)
  softmax_phase(L1, rows, tid, scr);
  // P3: hv = mish(LN(x @ vW1 + vb1)) -> L2
  gemm_bias_phase(L0, L2, Wp + 3 * 16384, vb1, rows, mq, nq, lane, quad, li);
  __syncthreads();
  ln_mish_pass(L2, vg, vbn, rows, tid);
  __syncthreads();
  // P4: hk = mish(LN(keys @ kW1 + kb1)) -> L0
  gemm_bias_phase(L1, L0, Wp + 1 * 16384, kb1, rows, mq, nq, lane, quad, li);
  __syncthreads();
  ln_mish_pass(L0, kg, kbn, rows, tid);
  __syncthreads();
  // P5: Z[s] = sum_rows (hv@vW2+vb2) * (hk@kW2+kb2)
  pairsum_phase(L2, Wp + 4 * 16384, vb2, L0, Wp + 2 * 16384, kb2, Z, s, rows,
                mq, nq, lane, quad, li, scr, tid);
  // P6: key0b = keys @ iW_map + ib_map -> L2
  gemm_bias_phase(L1, L2, Wp + 5 * 16384, ib_map, rows, mq, nq, lane, quad, li);
  __syncthreads();
  // P7: keys2 = softmax(key0b) (in place, L2)
  softmax_phase(L2, rows, tid, scr);
  // P8: hiv = mish(LN(keys @ ivW1 + ivb1)) -> L0
  gemm_bias_phase(L1, L0, Wp + 8 * 16384, ivb1, rows, mq, nq, lane, quad, li);
  __syncthreads();
  ln_mish_pass(L0, ivg, ivbn, rows, tid);
  __syncthreads();
  // P9: hik = mish(LN(keys2 @ ikW1 + ikb1)) -> L1 (keys dead after P8)
  gemm_bias_phase(L2, L1, Wp + 6 * 16384, ikb1, rows, mq, nq, lane, quad, li);
  __syncthreads();
  ln_mish_pass(L1, ikg, ikbn, rows, tid);
  __syncthreads();
  // P10: KE[s] = sum_rows (hiv@ivW2+ivb2) * (hik@ikW2+ikb2)
  pairsum_phase(L0, Wp + 9 * 16384, ivb2, L1, Wp + 7 * 16384, ikb2, KE, s, rows,
                mq, nq, lane, quad, li, scr, tid);
}

extern "C" void kernel_launch(void* const* d_in, const int* in_sizes, int n_in,
                              void* d_out, int out_size, void* d_ws, size_t ws_size,
                              hipStream_t stream) {
  const float* x = (const float*)d_in[0];
  const int* batch = (const int*)d_in[1];
  const int N = in_sizes[1];
  const float* W_map = (const float*)d_in[3];  const float* b_map = (const float*)d_in[4];
  const float* kW1 = (const float*)d_in[5];    const float* kb1 = (const float*)d_in[6];
  const float* kg = (const float*)d_in[7];     const float* kbn = (const float*)d_in[8];
  const float* kW2 = (const float*)d_in[9];    const float* kb2 = (const float*)d_in[10];
  const float* vW1 = (const float*)d_in[11];   const float* vb1 = (const float*)d_in[12];
  const float* vg = (const float*)d_in[13];    const float* vbn = (const float*)d_in[14];
  const float* vW2 = (const float*)d_in[15];   const float* vb2 = (const float*)d_in[16];
  const float* iW_map = (const float*)d_in[17];const float* ib_map = (const float*)d_in[18];
  const float* ikW1 = (const float*)d_in[19];  const float* ikb1 = (const float*)d_in[20];
  const float* ikg = (const float*)d_in[21];   const float* ikbn = (const float*)d_in[22];
  const float* ikW2 = (const float*)d_in[23];  const float* ikb2 = (const float*)d_in[24];
  const float* ivW1 = (const float*)d_in[25];  const float* ivb1 = (const float*)d_in[26];
  const float* ivg = (const float*)d_in[27];   const float* ivbn = (const float*)d_in[28];
  const float* ivW2 = (const float*)d_in[29];  const float* ivb2 = (const float*)d_in[30];

  char* ws = (char*)d_ws;
  int* seg = (int*)ws;            // 4097 ints
  f16* Wp = (f16*)(ws + 32768);   // 10 * 16384 f16 = 320 KB

  float* Z = (float*)d_out;
  float* KE = Z + (out_size / 2);

  seg_bounds<<<(NBATCH + 1 + 255) / 256, 256, 0, stream>>>(batch, N, NBATCH, seg);
  pack_weights<<<(10 * 16384) / 256, 256, 0, stream>>>(
      W_map, kW1, kW2, vW1, vW2, iW_map, ikW1, ikW2, ivW1, ivW2, Wp);

  encoder_mega<<<NBATCH, 1024, 0, stream>>>(
      x, seg, Wp, b_map, kb1, kg, kbn, kb2, vb1, vg, vbn, vb2,
      ib_map, ikb1, ikg, ikbn, ikb2, ivb1, ivg, ivbn, ivb2, Z, KE);
}

// Round 4
// 1381.879 us; speedup vs baseline: 1.0657x; 1.0657x over previous
//
#include <hip/hip_runtime.h>

typedef _Float16 f16;
typedef _Float16 f16x4 __attribute__((ext_vector_type(4)));
typedef _Float16 f16x8 __attribute__((ext_vector_type(8)));
typedef float f32x4 __attribute__((ext_vector_type(4)));

#define NBATCH 4096
#define RMAX 200   // max segment rows held in LDS; mean=122, sd~11, max over 4096 ~ 170

__device__ __forceinline__ f32x4 mfma16(f16x8 a, f16x8 b, f32x4 c) {
  return __builtin_amdgcn_mfma_f32_16x16x32_f16(a, b, c, 0, 0, 0);
}

// XOR swizzle: keeps 8-f16 chunks contiguous+16B-aligned, spreads row stride across banks
__device__ __forceinline__ int swz(int r, int c) { return r * 128 + (c ^ ((r & 7) << 3)); }

// ---------------- segment bounds: seg[s] = first i with batch[i] >= s ----------------
__global__ void seg_bounds(const int* __restrict__ batch, int N, int NB, int* __restrict__ seg) {
  int s = blockIdx.x * blockDim.x + threadIdx.x;
  if (s > NB) return;
  int lo = 0, hi = N;
  while (lo < hi) { int mid = (lo + hi) >> 1; if (batch[mid] < s) lo = mid + 1; else hi = mid; }
  seg[s] = lo;
}

// ---------------- pack 10 fp32 128x128 weights into MFMA B-frag order, fp16 ----------------
__global__ void pack_weights(const float* w0, const float* w1, const float* w2, const float* w3,
                             const float* w4, const float* w5, const float* w6, const float* w7,
                             const float* w8, const float* w9, f16* __restrict__ Wp) {
  int idx = blockIdx.x * blockDim.x + threadIdx.x;
  if (idx >= 10 * 16384) return;
  int w = idx >> 14, p = idx & 16383;
  int j = p & 7, lane = (p >> 3) & 63, nt = (p >> 9) & 7, kk = p >> 12;
  int k = kk * 32 + (lane >> 4) * 8 + j;
  int n = nt * 16 + (lane & 15);
  const float* W;
  switch (w) {
    case 0: W = w0; break; case 1: W = w1; break; case 2: W = w2; break;
    case 3: W = w3; break; case 4: W = w4; break; case 5: W = w5; break;
    case 6: W = w6; break; case 7: W = w7; break; case 8: W = w8; break;
    default: W = w9; break;
  }
  Wp[idx] = (f16)W[k * 128 + n];
}

// ---------------- in-LDS GEMM + bias: D[rows,128] = S[rows,128] @ W + b (fp16) ----------------
// 16 waves: mq = wave&3 owns m-tiles t ≡ mq (mod 4); nq = wave>>2 owns 32 cols (2 n-tiles).
__device__ __forceinline__ void gemm_bias_phase(const f16* S, f16* D, const f16* __restrict__ Wg,
    const float* __restrict__ bias, int rows, int mq, int nq, int lane, int quad, int li) {
  int ntl = (rows + 15) >> 4;
  f16x8 bF[4][2];
#pragma unroll
  for (int kk = 0; kk < 4; ++kk)
#pragma unroll
    for (int j = 0; j < 2; ++j)
      bF[kk][j] = *(const f16x8*)(Wg + (size_t)(((kk * 8 + nq * 2 + j) * 64 + lane) * 8));
  float bc[2];
#pragma unroll
  for (int j = 0; j < 2; ++j) bc[j] = bias[(nq * 2 + j) * 16 + li];
  for (int t = mq; t < ntl; t += 4) {
    int m0 = t * 16;
    f32x4 acc0 = {0.f, 0.f, 0.f, 0.f}, acc1 = {0.f, 0.f, 0.f, 0.f};
    int rl = m0 + li;
    bool ok = rl < rows;
#pragma unroll
    for (int kk = 0; kk < 4; ++kk) {
      f16x8 aF = {};
      if (ok) aF = *(const f16x8*)(S + swz(rl, kk * 32 + quad * 8));
      acc0 = mfma16(aF, bF[kk][0], acc0);
      acc1 = mfma16(aF, bF[kk][1], acc1);
    }
#pragma unroll
    for (int r = 0; r < 4; ++r) {
      int row = m0 + quad * 4 + r;
      if (row < rows) {
        D[swz(row, (nq * 2) * 16 + li)] = (f16)(acc0[r] + bc[0]);
        D[swz(row, (nq * 2 + 1) * 16 + li)] = (f16)(acc1[r] + bc[1]);
      }
    }
  }
}

// ---------------- in-LDS LayerNorm + Mish, in place; 4 threads/row, single shot ----------------
__device__ __forceinline__ void ln_mish_pass(f16* D, const float* __restrict__ g,
                                             const float* __restrict__ bn, int rows, int tid) {
  int part = tid & 3;
  int r = tid >> 2;               // 0..255 covers all rows (<= RMAX)
  if (r < rows) {
    float gv[32], bv[32];
#pragma unroll
    for (int j = 0; j < 8; ++j) {
      float4 gg = *(const float4*)(g + part * 32 + j * 4);
      float4 bb = *(const float4*)(bn + part * 32 + j * 4);
      gv[j * 4 + 0] = gg.x; gv[j * 4 + 1] = gg.y; gv[j * 4 + 2] = gg.z; gv[j * 4 + 3] = gg.w;
      bv[j * 4 + 0] = bb.x; bv[j * 4 + 1] = bb.y; bv[j * 4 + 2] = bb.z; bv[j * 4 + 3] = bb.w;
    }
    f16x8 v[4];
    float s1 = 0.f, s2 = 0.f;
#pragma unroll
    for (int j = 0; j < 4; ++j) {
      v[j] = *(const f16x8*)(D + swz(r, part * 32 + j * 8));
#pragma unroll
      for (int e = 0; e < 8; ++e) { float f = (float)v[j][e]; s1 += f; s2 += f * f; }
    }
    s1 += __shfl_xor(s1, 1, 64); s2 += __shfl_xor(s2, 1, 64);
    s1 += __shfl_xor(s1, 2, 64); s2 += __shfl_xor(s2, 2, 64);
    float mean = s1 * (1.f / 128.f);
    float var = s2 * (1.f / 128.f) - mean * mean;
    float rstd = rsqrtf(var + 1e-5f);
#pragma unroll
    for (int j = 0; j < 4; ++j) {
      f16x8 o;
#pragma unroll
      for (int e = 0; e < 8; ++e) {
        float u = ((float)v[j][e] - mean) * rstd * gv[j * 8 + e] + bv[j * 8 + e];
        float t = __expf(u);
        float w = t * t + 2.f * t;
        float res = (u > 20.f) ? u : u * (w / (w + 2.f));
        o[e] = (f16)res;
      }
      *(f16x8*)(D + swz(r, part * 32 + j * 8)) = o;
    }
  }
}

// ---------------- block-local per-column softmax, 3-pass LDS (low VGPR) ----------------
// 1024 threads: c = tid&127, stripe st = tid>>7 (8 stripes over rows).
__device__ __forceinline__ void softmax_phase(f16* P, int rows, int tid, float* scr) {
  int c = tid & 127, st = tid >> 7;
  // pass 1: stripe max
  float m = -3.4e38f;
  for (int r = st; r < rows; r += 8) m = fmaxf(m, (float)P[swz(r, c)]);
  scr[st * 128 + c] = m;
  __syncthreads();
  if (tid < 128) {
    float M = scr[tid];
#pragma unroll
    for (int k = 1; k < 8; ++k) M = fmaxf(M, scr[k * 128 + tid]);
    scr[tid] = M;
  }
  __syncthreads();
  float M = scr[c];
  // pass 2: e = exp(v - M) written back (fp16), stripe sum
  float d = 0.f;
  for (int r = st; r < rows; r += 8) {
    float e = __expf((float)P[swz(r, c)] - M);
    P[swz(r, c)] = (f16)e;
    d += e;
  }
  __syncthreads();  // all lanes have read scr[c] before reuse
  scr[st * 128 + c] = d;
  __syncthreads();
  if (tid < 128) {
    float D = 0.f;
#pragma unroll
    for (int k = 0; k < 8; ++k) D += scr[k * 128 + tid];
    scr[tid] = (D > 0.f) ? 1.f / D : 0.f;
  }
  __syncthreads();
  float inv = scr[c];
  // pass 3: scale
  for (int r = st; r < rows; r += 8)
    P[swz(r, c)] = (f16)((float)P[swz(r, c)] * inv);
  __syncthreads();
}

// ---------------- paired GEMMs + bias, product, block-local segment sum -> global row ----------------
__device__ __forceinline__ void pairsum_phase(const f16* S1, const f16* __restrict__ W1,
    const float* __restrict__ b1, const f16* S2, const f16* __restrict__ W2,
    const float* __restrict__ b2, float* __restrict__ outp, int s, int rows,
    int mq, int nq, int lane, int quad, int li, float* red, int tid) {
  f16x8 bF1[4][2], bF2[4][2];
#pragma unroll
  for (int kk = 0; kk < 4; ++kk)
#pragma unroll
    for (int j = 0; j < 2; ++j) {
      size_t off = (size_t)(((kk * 8 + nq * 2 + j) * 64 + lane) * 8);
      bF1[kk][j] = *(const f16x8*)(W1 + off);
      bF2[kk][j] = *(const f16x8*)(W2 + off);
    }
  float b1c[2], b2c[2];
#pragma unroll
  for (int j = 0; j < 2; ++j) {
    b1c[j] = b1[(nq * 2 + j) * 16 + li];
    b2c[j] = b2[(nq * 2 + j) * 16 + li];
  }
  float zs0 = 0.f, zs1 = 0.f;
  int ntl = (rows + 15) >> 4;
  for (int t = mq; t < ntl; t += 4) {
    int m0 = t * 16;
    f32x4 a10 = {0.f,0.f,0.f,0.f}, a11 = {0.f,0.f,0.f,0.f};
    f32x4 a20 = {0.f,0.f,0.f,0.f}, a21 = {0.f,0.f,0.f,0.f};
    int rl = m0 + li;
    bool ok = rl < rows;
#pragma unroll
    for (int kk = 0; kk < 4; ++kk) {
      f16x8 aF1 = {}, aF2 = {};
      if (ok) {
        aF1 = *(const f16x8*)(S1 + swz(rl, kk * 32 + quad * 8));
        aF2 = *(const f16x8*)(S2 + swz(rl, kk * 32 + quad * 8));
      }
      a10 = mfma16(aF1, bF1[kk][0], a10);
      a11 = mfma16(aF1, bF1[kk][1], a11);
      a20 = mfma16(aF2, bF2[kk][0], a20);
      a21 = mfma16(aF2, bF2[kk][1], a21);
    }
    float cs0 = 0.f, cs1 = 0.f;
#pragma unroll
    for (int r = 0; r < 4; ++r) {
      int row = m0 + quad * 4 + r;
      if (row < rows) {
        cs0 += (a10[r] + b1c[0]) * (a20[r] + b2c[0]);
        cs1 += (a11[r] + b1c[1]) * (a21[r] + b2c[1]);
      }
    }
    cs0 += __shfl_xor(cs0, 16, 64); cs0 += __shfl_xor(cs0, 32, 64);
    cs1 += __shfl_xor(cs1, 16, 64); cs1 += __shfl_xor(cs1, 32, 64);
    zs0 += cs0; zs1 += cs1;
  }
  int wave = tid >> 6;
  red[tid] = 0.f; red[tid + 1024] = 0.f;
  __syncthreads();
  if (quad == 0) {
    red[wave * 128 + (nq * 2) * 16 + li] = zs0;
    red[wave * 128 + (nq * 2 + 1) * 16 + li] = zs1;
  }
  __syncthreads();
  if (tid < 128) {
    float ssum = 0.f;
#pragma unroll
    for (int w = 0; w < 16; ++w) ssum += red[w * 128 + tid];
    outp[(size_t)s * 128 + tid] = ssum;
  }
  __syncthreads();
}

// ---------------- the fused per-segment encoder ----------------
// __launch_bounds__(1024, 4): 4 waves/EU = one 16-wave block/CU, VGPR cap 128.
// (bare __launch_bounds__(1024) capped VGPRs at 64 -> scratch spills, 707 MB of
//  spill WRITE_SIZE in R3 profiling. Do not remove the second argument.)
__global__ __launch_bounds__(1024, 4) void encoder_mega(
    const float* __restrict__ x, const int* __restrict__ seg, const f16* __restrict__ Wp,
    const float* b_map, const float* kb1, const float* kg, const float* kbn, const float* kb2,
    const float* vb1, const float* vg, const float* vbn, const float* vb2,
    const float* ib_map, const float* ikb1, const float* ikg, const float* ikbn,
    const float* ikb2, const float* ivb1, const float* ivg, const float* ivbn,
    const float* ivb2, float* __restrict__ Z, float* __restrict__ KE) {
  __shared__ f16 L0[RMAX * 128];
  __shared__ f16 L1[RMAX * 128];
  __shared__ f16 L2[RMAX * 128];
  __shared__ float scr[2048];   // softmax stripes (1024) / pairsum red (2048)
  int s = blockIdx.x;
  int a = seg[s], e = seg[s + 1];
  int rows = e - a;
  int tid = threadIdx.x;
  if (rows <= 0) {
    if (tid < 128) {
      Z[(size_t)s * 128 + tid] = 0.f;
      KE[(size_t)s * 128 + tid] = 0.f;
    }
    return;
  }
  if (rows > RMAX) rows = RMAX;  // statistically unreachable; prevents LDS corruption
  int lane = tid & 63, wave = tid >> 6, quad = lane >> 4, li = lane & 15;
  int mq = wave & 3, nq = wave >> 2;

  // P0: x -> L0 (fp16, swizzled)
  const float* xa = x + (size_t)a * 128;
  for (int i = tid * 4; i < rows * 128; i += 4096) {
    float4 v = *(const float4*)(xa + i);
    f16x4 h;
    h[0] = (f16)v.x; h[1] = (f16)v.y; h[2] = (f16)v.z; h[3] = (f16)v.w;
    *(f16x4*)(L0 + swz(i >> 7, i & 127)) = h;
  }
  __syncthreads();
  // P1: key0 = x @ W_map + b_map -> L1
  gemm_bias_phase(L0, L1, Wp + 0 * 16384, b_map, rows, mq, nq, lane, quad, li);
  __syncthreads();
  // P2: keys = softmax(key0)  (in place, L1)
  softmax_phase(L1, rows, tid, scr);
  // P3: hv = mish(LN(x @ vW1 + vb1)) -> L2
  gemm_bias_phase(L0, L2, Wp + 3 * 16384, vb1, rows, mq, nq, lane, quad, li);
  __syncthreads();
  ln_mish_pass(L2, vg, vbn, rows, tid);
  __syncthreads();
  // P4: hk = mish(LN(keys @ kW1 + kb1)) -> L0
  gemm_bias_phase(L1, L0, Wp + 1 * 16384, kb1, rows, mq, nq, lane, quad, li);
  __syncthreads();
  ln_mish_pass(L0, kg, kbn, rows, tid);
  __syncthreads();
  // P5: Z[s] = sum_rows (hv@vW2+vb2) * (hk@kW2+kb2)
  pairsum_phase(L2, Wp + 4 * 16384, vb2, L0, Wp + 2 * 16384, kb2, Z, s, rows,
                mq, nq, lane, quad, li, scr, tid);
  // P6: key0b = keys @ iW_map + ib_map -> L2
  gemm_bias_phase(L1, L2, Wp + 5 * 16384, ib_map, rows, mq, nq, lane, quad, li);
  __syncthreads();
  // P7: keys2 = softmax(key0b) (in place, L2)
  softmax_phase(L2, rows, tid, scr);
  // P8: hiv = mish(LN(keys @ ivW1 + ivb1)) -> L0
  gemm_bias_phase(L1, L0, Wp + 8 * 16384, ivb1, rows, mq, nq, lane, quad, li);
  __syncthreads();
  ln_mish_pass(L0, ivg, ivbn, rows, tid);
  __syncthreads();
  // P9: hik = mish(LN(keys2 @ ikW1 + ikb1)) -> L1 (keys dead after P8)
  gemm_bias_phase(L2, L1, Wp + 6 * 16384, ikb1, rows, mq, nq, lane, quad, li);
  __syncthreads();
  ln_mish_pass(L1, ikg, ikbn, rows, tid);
  __syncthreads();
  // P10: KE[s] = sum_rows (hiv@ivW2+ivb2) * (hik@ikW2+ikb2)
  pairsum_phase(L0, Wp + 9 * 16384, ivb2, L1, Wp + 7 * 16384, ikb2, KE, s, rows,
                mq, nq, lane, quad, li, scr, tid);
}

extern "C" void kernel_launch(void* const* d_in, const int* in_sizes, int n_in,
                              void* d_out, int out_size, void* d_ws, size_t ws_size,
                              hipStream_t stream) {
  const float* x = (const float*)d_in[0];
  const int* batch = (const int*)d_in[1];
  const int N = in_sizes[1];
  const float* W_map = (const float*)d_in[3];  const float* b_map = (const float*)d_in[4];
  const float* kW1 = (const float*)d_in[5];    const float* kb1 = (const float*)d_in[6];
  const float* kg = (const float*)d_in[7];     const float* kbn = (const float*)d_in[8];
  const float* kW2 = (const float*)d_in[9];    const float* kb2 = (const float*)d_in[10];
  const float* vW1 = (const float*)d_in[11];   const float* vb1 = (const float*)d_in[12];
  const float* vg = (const float*)d_in[13];    const float* vbn = (const float*)d_in[14];
  const float* vW2 = (const float*)d_in[15];   const float* vb2 = (const float*)d_in[16];
  const float* iW_map = (const float*)d_in[17];const float* ib_map = (const float*)d_in[18];
  const float* ikW1 = (const float*)d_in[19];  const float* ikb1 = (const float*)d_in[20];
  const float* ikg = (const float*)d_in[21];   const float* ikbn = (const float*)d_in[22];
  const float* ikW2 = (const float*)d_in[23];  const float* ikb2 = (const float*)d_in[24];
  const float* ivW1 = (const float*)d_in[25];  const float* ivb1 = (const float*)d_in[26];
  const float* ivg = (const float*)d_in[27];   const float* ivbn = (const float*)d_in[28];
  const float* ivW2 = (const float*)d_in[29];  const float* ivb2 = (const float*)d_in[30];

  char* ws = (char*)d_ws;
  int* seg = (int*)ws;            // 4097 ints
  f16* Wp = (f16*)(ws + 32768);   // 10 * 16384 f16 = 320 KB

  float* Z = (float*)d_out;
  float* KE = Z + (out_size / 2);

  seg_bounds<<<(NBATCH + 1 + 255) / 256, 256, 0, stream>>>(batch, N, NBATCH, seg);
  pack_weights<<<(10 * 16384) / 256, 256, 0, stream>>>(
      W_map, kW1, kW2, vW1, vW2, iW_map, ikW1, ikW2, ivW1, ivW2, Wp);

  encoder_mega<<<NBATCH, 1024, 0, stream>>>(
      x, seg, Wp, b_map, kb1, kg, kbn, kb2, vb1, vg, vbn, vb2,
      ib_map, ikb1, ikg, ikbn, ikb2, ivb1, ivg, ivbn, ivb2, Z, KE);
}